// Round 1
// 1215.347 us; speedup vs baseline: 1.2053x; 1.2053x over previous
//
#include <hip/hip_runtime.h>
#include <hip/hip_bf16.h>

typedef __attribute__((ext_vector_type(8))) short short8;
typedef __attribute__((ext_vector_type(4))) float float4v;

#define B_WIN 2048
#define NT 66
#define DIMC 256
#define NH 8
#define HD 32
#define MTOK (B_WIN * NT)    // 135168 token rows

// ws layout (bytes)
#define WS_WQKV 0            // [768][256] bf16 = 393216
#define WS_PW   393216       // [256][256] bf16 = 131072
#define WS_BMAT 524288       // BmatT [8][80(col)][80(row)] fp32 = 204800
#define WS_YBUF 729088       // [2048][66][256] bf16 = 69206016  (total ~69.9 MB)

// LDS pool layout (bytes), phase-unioned
#define OFF_XB   0           // phase A: x bf16 [66][264]  (stride 528 B)
#define OFF_WBUF 34848       // phase A: W chunk [96(+pad)][40] (stride 80 B)
#define OFF_QH   45088       // Q bf16 [66][40] (scale+bias folded)
#define OFF_KH   50368       // K bf16 [66][40]
#define OFF_VT   55648       // V^T bf16 [32][104] (stride 208 B), cols 66..103 zero
#define POOL_SZ  62304
// overlay (after phase A): P=exp(S) bf16 [80][104] (stride 208 B) on top of XB
#define OFF_P    0

static __device__ __forceinline__ unsigned short f2b(float f) {
    __hip_bfloat16 h = __float2bfloat16(f);
    return *reinterpret_cast<unsigned short*>(&h);
}

// ---------------------------------------------------------------------------
// prep: fp32->bf16 weight conversion + TRANSPOSED bias matrix with masking
// BmatT[h][col][row] so phase B can load 4 consecutive rows as one float4.
// ---------------------------------------------------------------------------
__global__ __launch_bounds__(256) void prep_kernel(
    const float* __restrict__ qkv_w, const float* __restrict__ pw,
    const float* __restrict__ btab, const int* __restrict__ tnp,
    unsigned short* __restrict__ wqkv_bf, unsigned short* __restrict__ pwbf,
    float* __restrict__ Bmat)
{
    int gid = blockIdx.x * 256 + threadIdx.x;
    if (gid < 768 * 256) wqkv_bf[gid] = f2b(qkv_w[gid]);
    if (gid < 256 * 256) pwbf[gid] = f2b(pw[gid]);
    if (gid < 8 * 80 * 80) {
        int h = gid / 6400, rem = gid % 6400;
        int j = rem / 80, i = rem % 80;        // j = key col, i = query row
        int tn = *tnp;
        float v;
        if (j >= NT) v = -1e30f;               // mask col-padding (P=0)
        else if (i >= NT || i < tn || j < tn) v = 0.f;  // token rows/cols: no bias
        else {
            int ri = i - tn, rj = j - tn;
            int bidx = (((ri >> 3) - (rj >> 3) + 7) * 15) + ((ri & 7) - (rj & 7) + 7);
            v = btab[bidx * NH + h];
        }
        Bmat[gid] = v;                         // layout [h][j][i]
    }
}

// ---------------------------------------------------------------------------
// fused per-(b,h): QKV GEMM -> QK^T(+bias,+exp) -> PV(/rowsum) -> y to ybuf
// grid 16384, b-major: b = blk >> 3, h = blk & 7 (8 heads of b run together
// so x[b] is L2/L3-hot). NO global atomics anymore.
// ---------------------------------------------------------------------------
__global__ __launch_bounds__(256, 2) void attn_fused_kernel(
    const float* __restrict__ x,
    const unsigned short* __restrict__ wqkv_bf,
    const float* __restrict__ qkv_b,
    const float* __restrict__ Bmat,
    unsigned short* __restrict__ ybuf)
{
    __shared__ __align__(16) char pool[POOL_SZ];
    __shared__ float rowsum[80];

    const int tid = threadIdx.x;
    const int l = tid & 63, w = tid >> 6;      // lane, wave
    const int q = l >> 4, cl = l & 15;         // quad, low-lane
    const int b = blockIdx.x >> 3, h = blockIdx.x & 7;
    const size_t xbase = (size_t)b * (NT * DIMC);

    // ---- setup: zero V^T, stage x -> bf16 LDS ----
    for (int i = tid; i < 32 * 104 / 2; i += 256)
        ((unsigned int*)(pool + OFF_VT))[i] = 0u;
    for (int i = tid; i < NT * 64; i += 256) {
        int m = i >> 6, c4 = (i & 63) << 2;
        float4 xv = *(const float4*)(x + xbase + m * DIMC + c4);
        unsigned short h4[4] = { f2b(xv.x), f2b(xv.y), f2b(xv.z), f2b(xv.w) };
        *(ulonglong1*)(pool + OFF_XB + m * 528 + c4 * 2) = *(ulonglong1*)h4;
    }
    __syncthreads();

    // ---- phase A: QKV = x @ Wqkv(96 rows for head h)^T, tiles 5m x 6n ----
    const int ntiles = (w < 2) ? 8 : 7;        // tiles t = w + 4i over 30
    float4v acc[8];
    #pragma unroll
    for (int i = 0; i < 8; ++i) acc[i] = (float4v){0.f, 0.f, 0.f, 0.f};

    for (int kc = 0; kc < 8; ++kc) {           // K chunks of 32
        for (int i = tid; i < 768; i += 256) { // stage 96x32 bf16 (ushort4)
            int r = i >> 3, c4 = (i & 7) << 2;
            int grow = ((r >> 5) << 8) + (h << 5) + (r & 31);
            *(ulonglong1*)(pool + OFF_WBUF + r * 80 + c4 * 2) =
                *(const ulonglong1*)(wqkv_bf + grow * DIMC + (kc << 5) + c4);
        }
        __syncthreads();
        for (int i = 0; i < ntiles; ++i) {
            int t = w + 4 * i, mt = t % 5, nt = t / 5;
            int am = min(mt * 16 + cl, NT - 1);
            short8 a = *(const short8*)(pool + OFF_XB + am * 528 + (kc << 6) + (q << 4));
            short8 bb = *(const short8*)(pool + OFF_WBUF + (nt * 16 + cl) * 80 + (q << 4));
            acc[i] = __builtin_amdgcn_mfma_f32_16x16x32_bf16(a, bb, acc[i], 0, 0, 0);
        }
        __syncthreads();
    }

    // write Q (scaled), K, V^T to LDS
    for (int i = 0; i < ntiles; ++i) {
        int t = w + 4 * i, mt = t % 5, nt = t / 5;
        int ng = nt * 16 + cl;                  // 0..95
        int src = ng >> 5, cn = ng & 31;
        float bias = qkv_b[(src << 8) + (h << 5) + cn];
        #pragma unroll
        for (int r = 0; r < 4; ++r) {
            int m = mt * 16 + (q << 2) + r;
            if (m < NT) {
                float v = acc[i][r] + bias;
                if (src == 0)
                    *(unsigned short*)(pool + OFF_QH + m * 80 + cn * 2) =
                        f2b(v * 0.17677669529663687f);
                else if (src == 1)
                    *(unsigned short*)(pool + OFF_KH + m * 80 + cn * 2) = f2b(v);
                else
                    *(unsigned short*)(pool + OFF_VT + cn * 208 + m * 2) = f2b(v);
            }
        }
    }
    __syncthreads();   // QKV visible; xb dead -> P overlay OK

    // zero rowsum + P pad cols 80..95
    for (int i = tid; i < 80; i += 256) rowsum[i] = 0.f;
    for (int i = tid; i < 320; i += 256) {
        int m = i >> 2, c4 = 80 + ((i & 3) << 2);
        unsigned short z4[4] = {0, 0, 0, 0};
        *(ulonglong1*)(pool + OFF_P + m * 208 + c4 * 2) = *(ulonglong1*)z4;
    }
    __syncthreads();

    // ---- phase B: P = exp(Q@K^T + BmatT), rowsum accumulated ----
    for (int t = w; t < 25; t += 4) {
        int mt = t / 5, jt = t % 5;
        int am = min(mt * 16 + cl, NT - 1);
        int bj = min(jt * 16 + cl, NT - 1);
        short8 a = *(const short8*)(pool + OFF_QH + am * 80 + (q << 4));
        short8 bb = *(const short8*)(pool + OFF_KH + bj * 80 + (q << 4));
        float4v s = __builtin_amdgcn_mfma_f32_16x16x32_bf16(
            a, bb, (float4v){0.f, 0.f, 0.f, 0.f}, 0, 0, 0);
        int col = jt * 16 + cl;
        // one vectorized bias load: BmatT[h][col][mt*16+q*4 .. +3]
        float4 bv = *(const float4*)(Bmat + ((h * 80 + col) * 80) + mt * 16 + (q << 2));
        float rs[4];
        #pragma unroll
        for (int r = 0; r < 4; ++r) {
            int row = mt * 16 + (q << 2) + r;
            float p = __expf(s[r] + ((const float*)&bv)[r]);
            *(unsigned short*)(pool + OFF_P + row * 208 + col * 2) = f2b(p);
            rs[r] = p;
        }
        #pragma unroll
        for (int off = 1; off < 16; off <<= 1) {
            #pragma unroll
            for (int r = 0; r < 4; ++r) rs[r] += __shfl_xor(rs[r], off, 64);
        }
        if (cl == 0) {
            #pragma unroll
            for (int r = 0; r < 4; ++r)
                atomicAdd(&rowsum[mt * 16 + (q << 2) + r], rs[r]);
        }
    }
    __syncthreads();

    // ---- phase C: y = (P @ V) / rowsum -> ybuf (coalesced bf16 stores) ----
    const int npv = (w < 2) ? 3 : 2;           // tiles t = w + 4i over 10 (5m x 2n)
    for (int i = 0; i < npv; ++i) {
        int t = w + 4 * i, mt = t % 5, nt = t / 5;
        float4v a4 = (float4v){0.f, 0.f, 0.f, 0.f};
        #pragma unroll
        for (int ks = 0; ks < 3; ++ks) {
            short8 a = *(const short8*)(pool + OFF_P + (mt * 16 + cl) * 208 + (ks << 6) + (q << 4));
            short8 bb = *(const short8*)(pool + OFF_VT + (nt * 16 + cl) * 208 + (ks << 6) + (q << 4));
            a4 = __builtin_amdgcn_mfma_f32_16x16x32_bf16(a, bb, a4, 0, 0, 0);
        }
        #pragma unroll
        for (int r = 0; r < 4; ++r) {
            int m = mt * 16 + (q << 2) + r;
            if (m < NT) {
                float inv = 1.f / rowsum[m];
                ybuf[xbase + m * DIMC + (h << 5) + nt * 16 + cl] = f2b(a4[r] * inv);
            }
        }
    }
}

// ---------------------------------------------------------------------------
// proj: out[M][256] = ybuf[M][256](bf16) @ proj_w^T(bf16) + pb, M = 135168
// 128x128 tile, 4 waves (2x2), each wave 64x64 = 4x4 frags of 16x16x32.
// grid = (M/128) * 2 = 2112.  Plain stores, no atomics.
// ---------------------------------------------------------------------------
__global__ __launch_bounds__(256) void proj_kernel(
    const unsigned short* __restrict__ ybuf,
    const unsigned short* __restrict__ pwbf,
    const float* __restrict__ pb,
    float* __restrict__ out)
{
    __shared__ __align__(16) char ldsA[128 * 80];   // stride 80 B (bank-safe)
    __shared__ __align__(16) char ldsB[128 * 80];
    const int tid = threadIdx.x;
    const int l = tid & 63, w = tid >> 6;
    const int q = l >> 4, cl = l & 15;
    const int nb = blockIdx.x & 1;
    const size_t arow0 = (size_t)(blockIdx.x >> 1) * 128;
    const int brow0 = nb * 128;
    const int wm = w >> 1, wn = w & 1;

    float4v acc[4][4];
    #pragma unroll
    for (int mi = 0; mi < 4; ++mi)
        #pragma unroll
        for (int ni = 0; ni < 4; ++ni)
            acc[mi][ni] = (float4v){0.f, 0.f, 0.f, 0.f};

    float pbv[4];
    #pragma unroll
    for (int ni = 0; ni < 4; ++ni)
        pbv[ni] = pb[brow0 + wn * 64 + ni * 16 + cl];

    for (int kc = 0; kc < 8; ++kc) {
        if (kc) __syncthreads();
        #pragma unroll
        for (int s = 0; s < 2; ++s) {          // stage A,B [128][32] bf16 chunks
            int e = tid + (s << 8);
            int r = e >> 2, c = (e & 3) << 3;  // row, col (ushorts)
            *(short8*)(ldsA + r * 80 + (c << 1)) =
                *(const short8*)(ybuf + (arow0 + r) * DIMC + (kc << 5) + c);
            *(short8*)(ldsB + r * 80 + (c << 1)) =
                *(const short8*)(pwbf + (size_t)(brow0 + r) * DIMC + (kc << 5) + c);
        }
        __syncthreads();
        short8 af[4], bf[4];
        #pragma unroll
        for (int mi = 0; mi < 4; ++mi)
            af[mi] = *(const short8*)(ldsA + (wm * 64 + mi * 16 + cl) * 80 + (q << 4));
        #pragma unroll
        for (int ni = 0; ni < 4; ++ni)
            bf[ni] = *(const short8*)(ldsB + (wn * 64 + ni * 16 + cl) * 80 + (q << 4));
        #pragma unroll
        for (int mi = 0; mi < 4; ++mi)
            #pragma unroll
            for (int ni = 0; ni < 4; ++ni)
                acc[mi][ni] = __builtin_amdgcn_mfma_f32_16x16x32_bf16(
                    af[mi], bf[ni], acc[mi][ni], 0, 0, 0);
    }

    #pragma unroll
    for (int mi = 0; mi < 4; ++mi) {
        #pragma unroll
        for (int ni = 0; ni < 4; ++ni) {
            int col = brow0 + wn * 64 + ni * 16 + cl;
            #pragma unroll
            for (int r = 0; r < 4; ++r) {
                size_t row = arow0 + wm * 64 + mi * 16 + (q << 2) + r;
                out[row * DIMC + col] = acc[mi][ni][r] + pbv[ni];
            }
        }
    }
}

extern "C" void kernel_launch(void* const* d_in, const int* in_sizes, int n_in,
                              void* d_out, int out_size, void* d_ws, size_t ws_size,
                              hipStream_t stream) {
    const float* x     = (const float*)d_in[0];
    const float* qkv_w = (const float*)d_in[1];
    const float* qkv_b = (const float*)d_in[2];
    const float* btab  = (const float*)d_in[3];
    const float* pw    = (const float*)d_in[4];
    const float* pb    = (const float*)d_in[5];
    const int*   tnp   = (const int*)d_in[6];
    float* out = (float*)d_out;

    unsigned short* wqkv_bf = (unsigned short*)((char*)d_ws + WS_WQKV);
    unsigned short* pwbf    = (unsigned short*)((char*)d_ws + WS_PW);
    float*          Bmat    = (float*)((char*)d_ws + WS_BMAT);
    unsigned short* ybuf    = (unsigned short*)((char*)d_ws + WS_YBUF);

    prep_kernel<<<768, 256, 0, stream>>>(qkv_w, pw, btab, tnp, wqkv_bf, pwbf, Bmat);
    attn_fused_kernel<<<B_WIN * NH, 256, 0, stream>>>(x, wqkv_bf, qkv_b, Bmat, ybuf);
    proj_kernel<<<(MTOK / 128) * 2, 256, 0, stream>>>(ybuf, pwbf, pb, out);
}

// Round 2
// 627.423 us; speedup vs baseline: 2.3347x; 1.9370x over previous
//
#include <hip/hip_runtime.h>
#include <hip/hip_bf16.h>

typedef __attribute__((ext_vector_type(8))) short short8;
typedef __attribute__((ext_vector_type(4))) float float4v;

#define B_WIN 2048
#define NT 66
#define DIMC 256
#define NH 8
#define HD 32
#define MTOK (B_WIN * NT)    // 135168 token rows

// ws layout (bytes)
#define WS_WQKV 0            // [768][256] bf16 = 393216
#define WS_PW   393216       // [256][256] bf16 = 131072
#define WS_BMAT 524288       // BmatT [8][80(col)][80(row)] fp32 = 204800 -> 729088
#define WS_XBF  729088       // [135168][256] bf16 = 69206016 -> 69935104
                             // (ybuf overlays WS_XBF after qkv_gemm is done)
#define WS_QKV  69935104     // [3][16384][66][32] bf16 = 207618048 -> 277553152
#define WS_NEEDED 277553152ull
#define QKV_PLANE 34603008   // 16384*66*32 elements per src plane

static __device__ __forceinline__ unsigned short f2b(float f) {
    __hip_bfloat16 h = __float2bfloat16(f);
    return *reinterpret_cast<unsigned short*>(&h);
}

// ---------------------------------------------------------------------------
// prep: fp32->bf16 weight conversion + TRANSPOSED bias matrix with masking
// BmatT[h][col][row] so QK^T epilogue loads 4 consecutive rows as one float4.
// ---------------------------------------------------------------------------
__global__ __launch_bounds__(256) void prep_kernel(
    const float* __restrict__ qkv_w, const float* __restrict__ pw,
    const float* __restrict__ btab, const int* __restrict__ tnp,
    unsigned short* __restrict__ wqkv_bf, unsigned short* __restrict__ pwbf,
    float* __restrict__ Bmat)
{
    int gid = blockIdx.x * 256 + threadIdx.x;
    if (gid < 768 * 256) wqkv_bf[gid] = f2b(qkv_w[gid]);
    if (gid < 256 * 256) pwbf[gid] = f2b(pw[gid]);
    if (gid < 8 * 80 * 80) {
        int h = gid / 6400, rem = gid % 6400;
        int j = rem / 80, i = rem % 80;        // j = key col, i = query row
        int tn = *tnp;
        float v;
        if (j >= NT) v = -1e30f;               // mask col-padding (P=0)
        else if (i >= NT || i < tn || j < tn) v = 0.f;  // token rows/cols: no bias
        else {
            int ri = i - tn, rj = j - tn;
            int bidx = (((ri >> 3) - (rj >> 3) + 7) * 15) + ((ri & 7) - (rj & 7) + 7);
            v = btab[bidx * NH + h];
        }
        Bmat[gid] = v;                         // layout [h][j][i]
    }
}

// ---------------------------------------------------------------------------
// xconv: x fp32 -> bf16, one pass
// ---------------------------------------------------------------------------
__global__ __launch_bounds__(256) void xconv_kernel(
    const float* __restrict__ x, unsigned short* __restrict__ xbf)
{
    const size_t n8 = (size_t)MTOK * DIMC / 8;   // 4325376
    size_t stride = (size_t)gridDim.x * 256;
    for (size_t i = (size_t)blockIdx.x * 256 + threadIdx.x; i < n8; i += stride) {
        size_t base = i * 8;
        float4 a = *(const float4*)(x + base);
        float4 b = *(const float4*)(x + base + 4);
        unsigned short h8[8] = { f2b(a.x), f2b(a.y), f2b(a.z), f2b(a.w),
                                 f2b(b.x), f2b(b.y), f2b(b.z), f2b(b.w) };
        *(short8*)(xbf + base) = *(short8*)h8;
    }
}

// ---------------------------------------------------------------------------
// qkv_gemm: qkv[M][768] = xbf[M][256] @ wqkv^T, bias + Q-scale folded,
// scattered to per-(b,h) layout qkvbuf[src][b*8+h][66][32] bf16.
// 128x128 tile, 4 waves (2x2), grid = 1056 * 6.
// ---------------------------------------------------------------------------
__global__ __launch_bounds__(256) void qkv_gemm_kernel(
    const unsigned short* __restrict__ xbf,
    const unsigned short* __restrict__ wqkv_bf,
    const float* __restrict__ qkv_b,
    unsigned short* __restrict__ qkvbuf)
{
    __shared__ __align__(16) char ldsA[128 * 80];   // stride 80 B (bank-safe)
    __shared__ __align__(16) char ldsB[128 * 80];
    const int tid = threadIdx.x;
    const int l = tid & 63, w = tid >> 6;
    const int q = l >> 4, cl = l & 15;
    const int mt = blockIdx.x / 6, nb = blockIdx.x % 6;
    const unsigned arow0 = (unsigned)mt * 128;
    const int brow0 = nb * 128;
    const int wm = w >> 1, wn = w & 1;

    float4v acc[4][4];
    #pragma unroll
    for (int mi = 0; mi < 4; ++mi)
        #pragma unroll
        for (int ni = 0; ni < 4; ++ni)
            acc[mi][ni] = (float4v){0.f, 0.f, 0.f, 0.f};

    float bias4[4], scl4[4];
    int h4[4], c4[4];
    size_t sp4[4];
    #pragma unroll
    for (int ni = 0; ni < 4; ++ni) {
        int col = brow0 + wn * 64 + ni * 16 + cl;   // 0..767
        bias4[ni] = qkv_b[col];
        int src = col >> 8;
        scl4[ni] = (src == 0) ? 0.17677669529663687f : 1.0f;
        h4[ni] = (col >> 5) & 7;
        c4[ni] = col & 31;
        sp4[ni] = (size_t)src * QKV_PLANE;
    }

    for (int kc = 0; kc < 8; ++kc) {
        if (kc) __syncthreads();
        #pragma unroll
        for (int s = 0; s < 2; ++s) {          // stage A,B [128][32] bf16 chunks
            int e = tid + (s << 8);
            int r = e >> 2, c = (e & 3) << 3;  // row, col (ushorts)
            *(short8*)(ldsA + r * 80 + (c << 1)) =
                *(const short8*)(xbf + (size_t)(arow0 + r) * DIMC + (kc << 5) + c);
            *(short8*)(ldsB + r * 80 + (c << 1)) =
                *(const short8*)(wqkv_bf + (size_t)(brow0 + r) * DIMC + (kc << 5) + c);
        }
        __syncthreads();
        short8 af[4], bf[4];
        #pragma unroll
        for (int mi = 0; mi < 4; ++mi)
            af[mi] = *(const short8*)(ldsA + (wm * 64 + mi * 16 + cl) * 80 + (q << 4));
        #pragma unroll
        for (int ni = 0; ni < 4; ++ni)
            bf[ni] = *(const short8*)(ldsB + (wn * 64 + ni * 16 + cl) * 80 + (q << 4));
        #pragma unroll
        for (int mi = 0; mi < 4; ++mi)
            #pragma unroll
            for (int ni = 0; ni < 4; ++ni)
                acc[mi][ni] = __builtin_amdgcn_mfma_f32_16x16x32_bf16(
                    af[mi], bf[ni], acc[mi][ni], 0, 0, 0);
    }

    #pragma unroll
    for (int mi = 0; mi < 4; ++mi) {
        #pragma unroll
        for (int r = 0; r < 4; ++r) {
            unsigned row = arow0 + wm * 64 + mi * 16 + (q << 2) + r;
            unsigned bb = row / 66u;
            unsigned m = row - bb * 66u;
            size_t rb = (size_t)bb * 8;
            #pragma unroll
            for (int ni = 0; ni < 4; ++ni) {
                float val = (acc[mi][ni][r] + bias4[ni]) * scl4[ni];
                qkvbuf[sp4[ni] + ((rb + h4[ni]) * 66 + m) * 32 + c4[ni]] = f2b(val);
            }
        }
    }
}

// ---------------------------------------------------------------------------
// attn_core: per-(b,h): stage Q,K,V^T -> QK^T(+bias,+exp,rowsum) -> PV -> ybuf
// LDS ~34 KB -> 4 blocks/CU. Only 2 barriers on the critical path.
// ---------------------------------------------------------------------------
#define AC_QH 0        // [66][80B]  5280
#define AC_KH 5280     // [66][80B]  -> 10560
#define AC_VT 10560    // [32][208B] -> 17216
#define AC_P  17216    // [80][208B] -> 33856
#define AC_SZ 33856

__global__ __launch_bounds__(256, 4) void attn_core_kernel(
    const unsigned short* __restrict__ qkvbuf,
    const float* __restrict__ Bmat,
    unsigned short* __restrict__ ybuf)
{
    __shared__ __align__(16) char pool[AC_SZ];
    __shared__ float rowsum[80];

    const int tid = threadIdx.x;
    const int l = tid & 63, w = tid >> 6;
    const int q = l >> 4, cl = l & 15;
    const int b = blockIdx.x >> 3, h = blockIdx.x & 7;
    const size_t head = (size_t)(b * 8 + h) * (NT * HD);
    const unsigned short* qsrc = qkvbuf + head;
    const unsigned short* ksrc = qsrc + (size_t)QKV_PLANE;
    const unsigned short* vsrc = ksrc + (size_t)QKV_PLANE;

    // zero VT (32x104 ushorts) + P pad cols 80..95 + rowsum
    for (int i = tid; i < 32 * 104 / 2; i += 256)
        ((unsigned int*)(pool + AC_VT))[i] = 0u;
    for (int i = tid; i < 640; i += 256) {
        int m = i >> 3, j = i & 7;
        *(unsigned int*)(pool + AC_P + m * 208 + 160 + j * 4) = 0u;
    }
    if (tid < 80) rowsum[tid] = 0.f;

    // stage Q,K (short8, coalesced)
    for (int i = tid; i < 528; i += 256) {
        int sel = (i >= 264);
        int j = sel ? i - 264 : i;
        int r = j >> 2, c8 = (j & 3) << 3;
        const unsigned short* s = (sel ? ksrc : qsrc) + r * 32 + c8;
        *(short8*)(pool + (sel ? AC_KH : AC_QH) + r * 80 + (c8 << 1)) =
            *(const short8*)s;
    }
    // stage V transposed (scalar scatter, small)
    for (int i = tid; i < NT * 32; i += 256) {
        int m = i >> 5, c = i & 31;
        *(unsigned short*)(pool + AC_VT + c * 208 + (m << 1)) = vsrc[i];
    }
    __syncthreads();

    // ---- P = exp(Q@K^T + BmatT), rowsum accumulated ----
    for (int t = w; t < 25; t += 4) {
        int mt = t / 5, jt = t % 5;
        int am = min(mt * 16 + cl, NT - 1);
        int bj = min(jt * 16 + cl, NT - 1);
        short8 a = *(const short8*)(pool + AC_QH + am * 80 + (q << 4));
        short8 bb = *(const short8*)(pool + AC_KH + bj * 80 + (q << 4));
        float4v s = __builtin_amdgcn_mfma_f32_16x16x32_bf16(
            a, bb, (float4v){0.f, 0.f, 0.f, 0.f}, 0, 0, 0);
        int col = jt * 16 + cl;
        float4 bv = *(const float4*)(Bmat + ((h * 80 + col) * 80) + mt * 16 + (q << 2));
        float rs[4];
        #pragma unroll
        for (int r = 0; r < 4; ++r) {
            int row = mt * 16 + (q << 2) + r;
            float p = __expf(s[r] + ((const float*)&bv)[r]);
            *(unsigned short*)(pool + AC_P + row * 208 + col * 2) = f2b(p);
            rs[r] = p;
        }
        #pragma unroll
        for (int off = 1; off < 16; off <<= 1) {
            #pragma unroll
            for (int r = 0; r < 4; ++r) rs[r] += __shfl_xor(rs[r], off, 64);
        }
        if (cl == 0) {
            #pragma unroll
            for (int r = 0; r < 4; ++r)
                atomicAdd(&rowsum[mt * 16 + (q << 2) + r], rs[r]);
        }
    }
    __syncthreads();

    // ---- y = (P @ V) / rowsum -> ybuf ----
    const int npv = (w < 2) ? 3 : 2;           // tiles t = w + 4i over 10 (5m x 2n)
    for (int i = 0; i < npv; ++i) {
        int t = w + 4 * i, mt = t % 5, nt = t / 5;
        float4v a4 = (float4v){0.f, 0.f, 0.f, 0.f};
        #pragma unroll
        for (int ks = 0; ks < 3; ++ks) {
            short8 a = *(const short8*)(pool + AC_P + (mt * 16 + cl) * 208 + (ks << 6) + (q << 4));
            short8 bb = *(const short8*)(pool + AC_VT + (nt * 16 + cl) * 208 + (ks << 6) + (q << 4));
            a4 = __builtin_amdgcn_mfma_f32_16x16x32_bf16(a, bb, a4, 0, 0, 0);
        }
        #pragma unroll
        for (int r = 0; r < 4; ++r) {
            int m = mt * 16 + (q << 2) + r;
            if (m < NT) {
                float inv = 1.f / rowsum[m];
                ybuf[(size_t)b * (NT * DIMC) + m * DIMC + (h << 5) + nt * 16 + cl] =
                    f2b(a4[r] * inv);
            }
        }
    }
}

// ---------------------------------------------------------------------------
// FALLBACK (ws too small): round-1 fused per-(b,h) kernel
// ---------------------------------------------------------------------------
#define OFF_XB   0
#define OFF_WBUF 34848
#define OFF_QH   45088
#define OFF_KH   50368
#define OFF_VT   55648
#define POOL_SZ  62304
#define OFF_P    0

__global__ __launch_bounds__(256, 2) void attn_fused_kernel(
    const float* __restrict__ x,
    const unsigned short* __restrict__ wqkv_bf,
    const float* __restrict__ qkv_b,
    const float* __restrict__ Bmat,
    unsigned short* __restrict__ ybuf)
{
    __shared__ __align__(16) char pool[POOL_SZ];
    __shared__ float rowsum[80];

    const int tid = threadIdx.x;
    const int l = tid & 63, w = tid >> 6;
    const int q = l >> 4, cl = l & 15;
    const int b = blockIdx.x >> 3, h = blockIdx.x & 7;
    const size_t xbase = (size_t)b * (NT * DIMC);

    for (int i = tid; i < 32 * 104 / 2; i += 256)
        ((unsigned int*)(pool + OFF_VT))[i] = 0u;
    for (int i = tid; i < NT * 64; i += 256) {
        int m = i >> 6, c4 = (i & 63) << 2;
        float4 xv = *(const float4*)(x + xbase + m * DIMC + c4);
        unsigned short h4[4] = { f2b(xv.x), f2b(xv.y), f2b(xv.z), f2b(xv.w) };
        *(ulonglong1*)(pool + OFF_XB + m * 528 + c4 * 2) = *(ulonglong1*)h4;
    }
    __syncthreads();

    const int ntiles = (w < 2) ? 8 : 7;
    float4v acc[8];
    #pragma unroll
    for (int i = 0; i < 8; ++i) acc[i] = (float4v){0.f, 0.f, 0.f, 0.f};

    for (int kc = 0; kc < 8; ++kc) {
        for (int i = tid; i < 768; i += 256) {
            int r = i >> 3, c4 = (i & 7) << 2;
            int grow = ((r >> 5) << 8) + (h << 5) + (r & 31);
            *(ulonglong1*)(pool + OFF_WBUF + r * 80 + c4 * 2) =
                *(const ulonglong1*)(wqkv_bf + grow * DIMC + (kc << 5) + c4);
        }
        __syncthreads();
        for (int i = 0; i < ntiles; ++i) {
            int t = w + 4 * i, mt = t % 5, nt = t / 5;
            int am = min(mt * 16 + cl, NT - 1);
            short8 a = *(const short8*)(pool + OFF_XB + am * 528 + (kc << 6) + (q << 4));
            short8 bb = *(const short8*)(pool + OFF_WBUF + (nt * 16 + cl) * 80 + (q << 4));
            acc[i] = __builtin_amdgcn_mfma_f32_16x16x32_bf16(a, bb, acc[i], 0, 0, 0);
        }
        __syncthreads();
    }

    for (int i = 0; i < ntiles; ++i) {
        int t = w + 4 * i, mt = t % 5, nt = t / 5;
        int ng = nt * 16 + cl;
        int src = ng >> 5, cn = ng & 31;
        float bias = qkv_b[(src << 8) + (h << 5) + cn];
        #pragma unroll
        for (int r = 0; r < 4; ++r) {
            int m = mt * 16 + (q << 2) + r;
            if (m < NT) {
                float v = acc[i][r] + bias;
                if (src == 0)
                    *(unsigned short*)(pool + OFF_QH + m * 80 + cn * 2) =
                        f2b(v * 0.17677669529663687f);
                else if (src == 1)
                    *(unsigned short*)(pool + OFF_KH + m * 80 + cn * 2) = f2b(v);
                else
                    *(unsigned short*)(pool + OFF_VT + cn * 208 + m * 2) = f2b(v);
            }
        }
    }
    __syncthreads();

    for (int i = tid; i < 80; i += 256) rowsum[i] = 0.f;
    for (int i = tid; i < 320; i += 256) {
        int m = i >> 2, c4 = 80 + ((i & 3) << 2);
        unsigned short z4[4] = {0, 0, 0, 0};
        *(ulonglong1*)(pool + OFF_P + m * 208 + c4 * 2) = *(ulonglong1*)z4;
    }
    __syncthreads();

    for (int t = w; t < 25; t += 4) {
        int mt = t / 5, jt = t % 5;
        int am = min(mt * 16 + cl, NT - 1);
        int bj = min(jt * 16 + cl, NT - 1);
        short8 a = *(const short8*)(pool + OFF_QH + am * 80 + (q << 4));
        short8 bb = *(const short8*)(pool + OFF_KH + bj * 80 + (q << 4));
        float4v s = __builtin_amdgcn_mfma_f32_16x16x32_bf16(
            a, bb, (float4v){0.f, 0.f, 0.f, 0.f}, 0, 0, 0);
        int col = jt * 16 + cl;
        float4 bv = *(const float4*)(Bmat + ((h * 80 + col) * 80) + mt * 16 + (q << 2));
        float rs[4];
        #pragma unroll
        for (int r = 0; r < 4; ++r) {
            int row = mt * 16 + (q << 2) + r;
            float p = __expf(s[r] + ((const float*)&bv)[r]);
            *(unsigned short*)(pool + OFF_P + row * 208 + col * 2) = f2b(p);
            rs[r] = p;
        }
        #pragma unroll
        for (int off = 1; off < 16; off <<= 1) {
            #pragma unroll
            for (int r = 0; r < 4; ++r) rs[r] += __shfl_xor(rs[r], off, 64);
        }
        if (cl == 0) {
            #pragma unroll
            for (int r = 0; r < 4; ++r)
                atomicAdd(&rowsum[mt * 16 + (q << 2) + r], rs[r]);
        }
    }
    __syncthreads();

    const int npv = (w < 2) ? 3 : 2;
    for (int i = 0; i < npv; ++i) {
        int t = w + 4 * i, mt = t % 5, nt = t / 5;
        float4v a4 = (float4v){0.f, 0.f, 0.f, 0.f};
        #pragma unroll
        for (int ks = 0; ks < 3; ++ks) {
            short8 a = *(const short8*)(pool + OFF_P + (mt * 16 + cl) * 208 + (ks << 6) + (q << 4));
            short8 bb = *(const short8*)(pool + OFF_VT + (nt * 16 + cl) * 208 + (ks << 6) + (q << 4));
            a4 = __builtin_amdgcn_mfma_f32_16x16x32_bf16(a, bb, a4, 0, 0, 0);
        }
        #pragma unroll
        for (int r = 0; r < 4; ++r) {
            int m = mt * 16 + (q << 2) + r;
            if (m < NT) {
                float inv = 1.f / rowsum[m];
                ybuf[xbase + m * DIMC + (h << 5) + nt * 16 + cl] = f2b(a4[r] * inv);
            }
        }
    }
}

// ---------------------------------------------------------------------------
// proj: out[M][256] = ybuf[M][256](bf16) @ proj_w^T(bf16) + pb
// ---------------------------------------------------------------------------
__global__ __launch_bounds__(256) void proj_kernel(
    const unsigned short* __restrict__ ybuf,
    const unsigned short* __restrict__ pwbf,
    const float* __restrict__ pb,
    float* __restrict__ out)
{
    __shared__ __align__(16) char ldsA[128 * 80];
    __shared__ __align__(16) char ldsB[128 * 80];
    const int tid = threadIdx.x;
    const int l = tid & 63, w = tid >> 6;
    const int q = l >> 4, cl = l & 15;
    const int nb = blockIdx.x & 1;
    const size_t arow0 = (size_t)(blockIdx.x >> 1) * 128;
    const int brow0 = nb * 128;
    const int wm = w >> 1, wn = w & 1;

    float4v acc[4][4];
    #pragma unroll
    for (int mi = 0; mi < 4; ++mi)
        #pragma unroll
        for (int ni = 0; ni < 4; ++ni)
            acc[mi][ni] = (float4v){0.f, 0.f, 0.f, 0.f};

    float pbv[4];
    #pragma unroll
    for (int ni = 0; ni < 4; ++ni)
        pbv[ni] = pb[brow0 + wn * 64 + ni * 16 + cl];

    for (int kc = 0; kc < 8; ++kc) {
        if (kc) __syncthreads();
        #pragma unroll
        for (int s = 0; s < 2; ++s) {
            int e = tid + (s << 8);
            int r = e >> 2, c = (e & 3) << 3;
            *(short8*)(ldsA + r * 80 + (c << 1)) =
                *(const short8*)(ybuf + (arow0 + r) * DIMC + (kc << 5) + c);
            *(short8*)(ldsB + r * 80 + (c << 1)) =
                *(const short8*)(pwbf + (size_t)(brow0 + r) * DIMC + (kc << 5) + c);
        }
        __syncthreads();
        short8 af[4], bf[4];
        #pragma unroll
        for (int mi = 0; mi < 4; ++mi)
            af[mi] = *(const short8*)(ldsA + (wm * 64 + mi * 16 + cl) * 80 + (q << 4));
        #pragma unroll
        for (int ni = 0; ni < 4; ++ni)
            bf[ni] = *(const short8*)(ldsB + (wn * 64 + ni * 16 + cl) * 80 + (q << 4));
        #pragma unroll
        for (int mi = 0; mi < 4; ++mi)
            #pragma unroll
            for (int ni = 0; ni < 4; ++ni)
                acc[mi][ni] = __builtin_amdgcn_mfma_f32_16x16x32_bf16(
                    af[mi], bf[ni], acc[mi][ni], 0, 0, 0);
    }

    #pragma unroll
    for (int mi = 0; mi < 4; ++mi) {
        #pragma unroll
        for (int ni = 0; ni < 4; ++ni) {
            int col = brow0 + wn * 64 + ni * 16 + cl;
            #pragma unroll
            for (int r = 0; r < 4; ++r) {
                size_t row = arow0 + wm * 64 + mi * 16 + (q << 2) + r;
                out[row * DIMC + col] = acc[mi][ni][r] + pbv[ni];
            }
        }
    }
}

extern "C" void kernel_launch(void* const* d_in, const int* in_sizes, int n_in,
                              void* d_out, int out_size, void* d_ws, size_t ws_size,
                              hipStream_t stream) {
    const float* x     = (const float*)d_in[0];
    const float* qkv_w = (const float*)d_in[1];
    const float* qkv_b = (const float*)d_in[2];
    const float* btab  = (const float*)d_in[3];
    const float* pw    = (const float*)d_in[4];
    const float* pb    = (const float*)d_in[5];
    const int*   tnp   = (const int*)d_in[6];
    float* out = (float*)d_out;

    unsigned short* wqkv_bf = (unsigned short*)((char*)d_ws + WS_WQKV);
    unsigned short* pwbf    = (unsigned short*)((char*)d_ws + WS_PW);
    float*          Bmat    = (float*)((char*)d_ws + WS_BMAT);
    unsigned short* xbf     = (unsigned short*)((char*)d_ws + WS_XBF);
    unsigned short* ybuf    = (unsigned short*)((char*)d_ws + WS_XBF);  // overlay
    unsigned short* qkvbuf  = (unsigned short*)((char*)d_ws + WS_QKV);

    prep_kernel<<<768, 256, 0, stream>>>(qkv_w, pw, btab, tnp, wqkv_bf, pwbf, Bmat);

    if (ws_size >= WS_NEEDED) {
        xconv_kernel<<<4096, 256, 0, stream>>>(x, xbf);
        qkv_gemm_kernel<<<(MTOK / 128) * 6, 256, 0, stream>>>(xbf, wqkv_bf, qkv_b, qkvbuf);
        attn_core_kernel<<<B_WIN * NH, 256, 0, stream>>>(qkvbuf, Bmat, ybuf);
    } else {
        attn_fused_kernel<<<B_WIN * NH, 256, 0, stream>>>(x, wqkv_bf, qkv_b, Bmat, ybuf);
    }
    proj_kernel<<<(MTOK / 128) * 2, 256, 0, stream>>>(ybuf, pwbf, pb, out);
}

// Round 3
// 518.386 us; speedup vs baseline: 2.8258x; 1.2103x over previous
//
#include <hip/hip_runtime.h>
#include <hip/hip_bf16.h>

typedef __attribute__((ext_vector_type(8))) short short8;
typedef __attribute__((ext_vector_type(4))) float float4v;

#define B_WIN 2048
#define NT 66
#define DIMC 256
#define NH 8
#define HD 32
#define MTOK (B_WIN * NT)    // 135168 token rows

// ws layout (bytes)
#define WS_WQKV 0            // [768][256] bf16 = 393216
#define WS_PW   393216       // [256][256] bf16 = 131072
#define WS_BMAT 524288       // BmatT [8][80(col)][80(row)] fp32 (log2e-scaled) -> 729088
#define WS_XBF  729088       // [135168][256] bf16 = 69206016 -> 69935104
                             // (ybuf overlays WS_XBF after qkv_gemm is done)
#define WS_QKV  69935104     // [3][16384][66][32] bf16 = 207618048 -> 277553152
#define WS_NEEDED 277553152ull
#define QKV_PLANE 34603008   // 16384*66*32 elements per src plane

#define LOG2E 1.4426950408889634f

static __device__ __forceinline__ unsigned short f2b(float f) {
    __hip_bfloat16 h = __float2bfloat16(f);
    return *reinterpret_cast<unsigned short*>(&h);
}

// ---------------------------------------------------------------------------
// prep: weight fp32->bf16, Bmat (transposed, masked, *log2e), x fp32->bf16.
// grid 4096 grid-stride for x; first blocks also do the small conversions.
// ---------------------------------------------------------------------------
__global__ __launch_bounds__(256) void prep_kernel(
    const float* __restrict__ qkv_w, const float* __restrict__ pw,
    const float* __restrict__ btab, const int* __restrict__ tnp,
    const float* __restrict__ x,
    unsigned short* __restrict__ wqkv_bf, unsigned short* __restrict__ pwbf,
    float* __restrict__ Bmat, unsigned short* __restrict__ xbf)
{
    int gid = blockIdx.x * 256 + threadIdx.x;
    if (gid < 768 * 256) wqkv_bf[gid] = f2b(qkv_w[gid]);
    if (gid < 256 * 256) pwbf[gid] = f2b(pw[gid]);
    if (gid < 8 * 80 * 80) {
        int h = gid / 6400, rem = gid % 6400;
        int j = rem / 80, i = rem % 80;        // j = key col, i = query row
        int tn = *tnp;
        float v;
        if (j >= NT) v = -1e30f;               // mask col-padding (P=0)
        else if (i >= NT || i < tn || j < tn) v = 0.f;  // token rows/cols: no bias
        else {
            int ri = i - tn, rj = j - tn;
            int bidx = (((ri >> 3) - (rj >> 3) + 7) * 15) + ((ri & 7) - (rj & 7) + 7);
            v = btab[bidx * NH + h];
        }
        Bmat[gid] = v * LOG2E;                 // layout [h][j][i], exp2-ready
    }
    // x conversion, grid-stride
    const size_t n8 = (size_t)MTOK * DIMC / 8;
    size_t stride = (size_t)gridDim.x * 256;
    for (size_t i = (size_t)gid; i < n8; i += stride) {
        size_t base = i * 8;
        float4 a = *(const float4*)(x + base);
        float4 b = *(const float4*)(x + base + 4);
        unsigned short h8[8] = { f2b(a.x), f2b(a.y), f2b(a.z), f2b(a.w),
                                 f2b(b.x), f2b(b.y), f2b(b.z), f2b(b.w) };
        *(short8*)(xbf + base) = *(short8*)h8;
    }
}

// ---------------------------------------------------------------------------
// qkv_gemm: qkv[M][768] = xbf[M][256] @ wqkv^T, bias + Q-scale(*log2e) folded,
// scattered to per-(b,h) layout qkvbuf[src][b*8+h][66][32] bf16.
// ---------------------------------------------------------------------------
__global__ __launch_bounds__(256) void qkv_gemm_kernel(
    const unsigned short* __restrict__ xbf,
    const unsigned short* __restrict__ wqkv_bf,
    const float* __restrict__ qkv_b,
    unsigned short* __restrict__ qkvbuf)
{
    __shared__ __align__(16) char ldsA[128 * 80];   // stride 80 B (bank-safe)
    __shared__ __align__(16) char ldsB[128 * 80];
    const int tid = threadIdx.x;
    const int l = tid & 63, w = tid >> 6;
    const int q = l >> 4, cl = l & 15;
    const int mt = blockIdx.x / 6, nb = blockIdx.x % 6;
    const unsigned arow0 = (unsigned)mt * 128;
    const int brow0 = nb * 128;
    const int wm = w >> 1, wn = w & 1;

    float4v acc[4][4];
    #pragma unroll
    for (int mi = 0; mi < 4; ++mi)
        #pragma unroll
        for (int ni = 0; ni < 4; ++ni)
            acc[mi][ni] = (float4v){0.f, 0.f, 0.f, 0.f};

    float bias4[4], scl4[4];
    int h4[4], c4[4];
    size_t sp4[4];
    #pragma unroll
    for (int ni = 0; ni < 4; ++ni) {
        int col = brow0 + wn * 64 + ni * 16 + cl;   // 0..767
        bias4[ni] = qkv_b[col];
        int src = col >> 8;
        scl4[ni] = (src == 0) ? (0.17677669529663687f * LOG2E) : 1.0f;
        h4[ni] = (col >> 5) & 7;
        c4[ni] = col & 31;
        sp4[ni] = (size_t)src * QKV_PLANE;
    }

    for (int kc = 0; kc < 8; ++kc) {
        if (kc) __syncthreads();
        #pragma unroll
        for (int s = 0; s < 2; ++s) {          // stage A,B [128][32] bf16 chunks
            int e = tid + (s << 8);
            int r = e >> 2, c = (e & 3) << 3;  // row, col (ushorts)
            *(short8*)(ldsA + r * 80 + (c << 1)) =
                *(const short8*)(xbf + (size_t)(arow0 + r) * DIMC + (kc << 5) + c);
            *(short8*)(ldsB + r * 80 + (c << 1)) =
                *(const short8*)(wqkv_bf + (size_t)(brow0 + r) * DIMC + (kc << 5) + c);
        }
        __syncthreads();
        short8 af[4], bf[4];
        #pragma unroll
        for (int mi = 0; mi < 4; ++mi)
            af[mi] = *(const short8*)(ldsA + (wm * 64 + mi * 16 + cl) * 80 + (q << 4));
        #pragma unroll
        for (int ni = 0; ni < 4; ++ni)
            bf[ni] = *(const short8*)(ldsB + (wn * 64 + ni * 16 + cl) * 80 + (q << 4));
        #pragma unroll
        for (int mi = 0; mi < 4; ++mi)
            #pragma unroll
            for (int ni = 0; ni < 4; ++ni)
                acc[mi][ni] = __builtin_amdgcn_mfma_f32_16x16x32_bf16(
                    af[mi], bf[ni], acc[mi][ni], 0, 0, 0);
    }

    #pragma unroll
    for (int mi = 0; mi < 4; ++mi) {
        #pragma unroll
        for (int r = 0; r < 4; ++r) {
            unsigned row = arow0 + wm * 64 + mi * 16 + (q << 2) + r;
            unsigned bb = row / 66u;
            unsigned m = row - bb * 66u;
            size_t rb = (size_t)bb * 8;
            #pragma unroll
            for (int ni = 0; ni < 4; ++ni) {
                float val = (acc[mi][ni][r] + bias4[ni]) * scl4[ni];
                qkvbuf[sp4[ni] + ((rb + h4[ni]) * 66 + m) * 32 + c4[ni]] = f2b(val);
            }
        }
    }
}

// ---------------------------------------------------------------------------
// attn_core: per-(b,h): stage Q,K,V^T -> QK^T(+bias,exp2) -> PV(+ones col for
// rowsum via MFMA) -> normalize -> ybuf. No shuffles, no atomics.
// LDS ~37.5 KB -> 4 blocks/CU.
// ---------------------------------------------------------------------------
#define AC_QH 0        // [66][80B]   5280
#define AC_KH 5280     // [66][80B]  -> 10560
#define AC_VT 10560    // [48][208B] -> 20544 (row 32 = ones; 33..47 garbage-ok)
#define AC_P  20544    // [80][208B] -> 37184
#define AC_SZ 37184

__global__ __launch_bounds__(256, 4) void attn_core_kernel(
    const unsigned short* __restrict__ qkvbuf,
    const float* __restrict__ Bmat,
    unsigned short* __restrict__ ybuf)
{
    __shared__ __align__(16) char pool[AC_SZ];
    __shared__ float rowsum[80];

    const int tid = threadIdx.x;
    const int l = tid & 63, w = tid >> 6;
    const int q = l >> 4, cl = l & 15;
    const int b = blockIdx.x >> 3, h = blockIdx.x & 7;
    const size_t head = (size_t)(b * 8 + h) * (NT * HD);
    const unsigned short* qsrc = qkvbuf + head;
    const unsigned short* ksrc = qsrc + (size_t)QKV_PLANE;
    const unsigned short* vsrc = ksrc + (size_t)QKV_PLANE;

    // ---- issue global loads first (T14: latency hides under LDS init) ----
    // 264 short8 per plane; threads 0..255 take i=tid, tid<8 also i=256+tid
    short8 rq0 = *(const short8*)(qsrc + (size_t)tid * 8);
    short8 rk0 = *(const short8*)(ksrc + (size_t)tid * 8);
    short8 rv0 = *(const short8*)(vsrc + (size_t)tid * 8);
    short8 rq1, rk1, rv1;
    if (tid < 8) {
        rq1 = *(const short8*)(qsrc + (size_t)(256 + tid) * 8);
        rk1 = *(const short8*)(ksrc + (size_t)(256 + tid) * 8);
        rv1 = *(const short8*)(vsrc + (size_t)(256 + tid) * 8);
    }

    // ---- LDS init (independent of loads) ----
    // VT pad: rows 0..31, k-cols 66..97 <- 0 (16 dwords per row from byte 132)
    #pragma unroll
    for (int s = 0; s < 2; ++s) {
        int i = tid + (s << 8);
        int row = i >> 4, j = i & 15;
        *(unsigned int*)(pool + AC_VT + row * 208 + 132 + j * 4) = 0u;
    }
    // ones row 32: k-cols 0..95
    if (tid < 48)
        *(unsigned int*)(pool + AC_VT + 32 * 208 + tid * 4) = 0x3F803F80u;
    // P pad: cols 80..95 <- 0
    for (int i = tid; i < 640; i += 256) {
        int m = i >> 3, j = i & 7;
        *(unsigned int*)(pool + AC_P + m * 208 + 160 + j * 4) = 0u;
    }

    // ---- write staged regs to LDS ----
    {
        int r = tid >> 2, c8 = (tid & 3) << 3;
        *(short8*)(pool + AC_QH + r * 80 + (c8 << 1)) = rq0;
        *(short8*)(pool + AC_KH + r * 80 + (c8 << 1)) = rk0;
        #pragma unroll
        for (int e = 0; e < 8; ++e)
            *(unsigned short*)(pool + AC_VT + (c8 + e) * 208 + (r << 1)) =
                ((unsigned short*)&rv0)[e];
        if (tid < 8) {
            int r1 = 64 + (tid >> 2), c81 = (tid & 3) << 3;
            *(short8*)(pool + AC_QH + r1 * 80 + (c81 << 1)) = rq1;
            *(short8*)(pool + AC_KH + r1 * 80 + (c81 << 1)) = rk1;
            #pragma unroll
            for (int e = 0; e < 8; ++e)
                *(unsigned short*)(pool + AC_VT + (c81 + e) * 208 + (r1 << 1)) =
                    ((unsigned short*)&rv1)[e];
        }
    }
    __syncthreads();

    // ---- phase B: P = exp2(Q@K^T + BmatT)  (scales pre-folded) ----
    for (int t = w; t < 25; t += 4) {
        int mt = t / 5, jt = t - mt * 5;
        short8 a = *(const short8*)(pool + AC_QH + (mt * 16 + cl) * 80 + (q << 4));
        short8 bb = *(const short8*)(pool + AC_KH + (jt * 16 + cl) * 80 + (q << 4));
        float4v s = __builtin_amdgcn_mfma_f32_16x16x32_bf16(
            a, bb, (float4v){0.f, 0.f, 0.f, 0.f}, 0, 0, 0);
        int col = jt * 16 + cl;
        float4 bv = *(const float4*)(Bmat + ((h * 80 + col) * 80) + mt * 16 + (q << 2));
        #pragma unroll
        for (int r = 0; r < 4; ++r) {
            float p = exp2f(s[r] + ((const float*)&bv)[r]);
            *(unsigned short*)(pool + AC_P + (mt * 16 + (q << 2) + r) * 208 + col * 2) = f2b(p);
        }
    }
    __syncthreads();

    // ---- phase C: PV with ones-column (nt==2 gives rowsum via MFMA) ----
    float4v yac[4];
    int mts[4], nts[4];
    #pragma unroll
    for (int i = 0; i < 4; ++i) {
        int t = w + 4 * i;
        mts[i] = -1; nts[i] = -1;
        if (t < 15) {
            int mt = t / 3, nt = t - mt * 3;
            mts[i] = mt; nts[i] = nt;
            float4v a4 = (float4v){0.f, 0.f, 0.f, 0.f};
            #pragma unroll
            for (int ks = 0; ks < 3; ++ks) {
                short8 a = *(const short8*)(pool + AC_P + (mt * 16 + cl) * 208 + (ks << 6) + (q << 4));
                short8 bb = *(const short8*)(pool + AC_VT + (nt * 16 + cl) * 208 + (ks << 6) + (q << 4));
                a4 = __builtin_amdgcn_mfma_f32_16x16x32_bf16(a, bb, a4, 0, 0, 0);
            }
            yac[i] = a4;
            if (nt == 2 && cl == 0) {
                #pragma unroll
                for (int r = 0; r < 4; ++r)
                    rowsum[mt * 16 + (q << 2) + r] = a4[r];
            }
        }
    }
    __syncthreads();

    // ---- normalize + store ----
    #pragma unroll
    for (int i = 0; i < 4; ++i) {
        if (mts[i] >= 0 && nts[i] != 2) {
            int mt = mts[i], nt = nts[i];
            #pragma unroll
            for (int r = 0; r < 4; ++r) {
                int m = mt * 16 + (q << 2) + r;
                if (m < NT) {
                    float inv = 1.f / rowsum[m];
                    ybuf[(size_t)b * (NT * DIMC) + m * DIMC + (h << 5) + nt * 16 + cl] =
                        f2b(yac[i][r] * inv);
                }
            }
        }
    }
}

// ---------------------------------------------------------------------------
// FALLBACK (ws too small): round-1 fused per-(b,h) kernel (exp2 convention)
// ---------------------------------------------------------------------------
#define OFF_XB   0
#define OFF_WBUF 34848
#define OFF_QH   45088
#define OFF_KH   50368
#define OFF_VT   55648
#define POOL_SZ  62304
#define OFF_P    0

__global__ __launch_bounds__(256, 2) void attn_fused_kernel(
    const float* __restrict__ x,
    const unsigned short* __restrict__ wqkv_bf,
    const float* __restrict__ qkv_b,
    const float* __restrict__ Bmat,
    unsigned short* __restrict__ ybuf)
{
    __shared__ __align__(16) char pool[POOL_SZ];
    __shared__ float rowsum[80];

    const int tid = threadIdx.x;
    const int l = tid & 63, w = tid >> 6;
    const int q = l >> 4, cl = l & 15;
    const int b = blockIdx.x >> 3, h = blockIdx.x & 7;
    const size_t xbase = (size_t)b * (NT * DIMC);

    for (int i = tid; i < 32 * 104 / 2; i += 256)
        ((unsigned int*)(pool + OFF_VT))[i] = 0u;
    for (int i = tid; i < NT * 64; i += 256) {
        int m = i >> 6, c4 = (i & 63) << 2;
        float4 xv = *(const float4*)(x + xbase + m * DIMC + c4);
        unsigned short h4[4] = { f2b(xv.x), f2b(xv.y), f2b(xv.z), f2b(xv.w) };
        *(ulonglong1*)(pool + OFF_XB + m * 528 + c4 * 2) = *(ulonglong1*)h4;
    }
    __syncthreads();

    const int ntiles = (w < 2) ? 8 : 7;
    float4v acc[8];
    #pragma unroll
    for (int i = 0; i < 8; ++i) acc[i] = (float4v){0.f, 0.f, 0.f, 0.f};

    for (int kc = 0; kc < 8; ++kc) {
        for (int i = tid; i < 768; i += 256) {
            int r = i >> 3, c4 = (i & 7) << 2;
            int grow = ((r >> 5) << 8) + (h << 5) + (r & 31);
            *(ulonglong1*)(pool + OFF_WBUF + r * 80 + c4 * 2) =
                *(const ulonglong1*)(wqkv_bf + grow * DIMC + (kc << 5) + c4);
        }
        __syncthreads();
        for (int i = 0; i < ntiles; ++i) {
            int t = w + 4 * i, mt = t % 5, nt = t / 5;
            int am = min(mt * 16 + cl, NT - 1);
            short8 a = *(const short8*)(pool + OFF_XB + am * 528 + (kc << 6) + (q << 4));
            short8 bb = *(const short8*)(pool + OFF_WBUF + (nt * 16 + cl) * 80 + (q << 4));
            acc[i] = __builtin_amdgcn_mfma_f32_16x16x32_bf16(a, bb, acc[i], 0, 0, 0);
        }
        __syncthreads();
    }

    for (int i = 0; i < ntiles; ++i) {
        int t = w + 4 * i, mt = t % 5, nt = t / 5;
        int ng = nt * 16 + cl;
        int src = ng >> 5, cn = ng & 31;
        float bias = qkv_b[(src << 8) + (h << 5) + cn];
        #pragma unroll
        for (int r = 0; r < 4; ++r) {
            int m = mt * 16 + (q << 2) + r;
            if (m < NT) {
                float v = acc[i][r] + bias;
                if (src == 0)
                    *(unsigned short*)(pool + OFF_QH + m * 80 + cn * 2) =
                        f2b(v * (0.17677669529663687f * LOG2E));
                else if (src == 1)
                    *(unsigned short*)(pool + OFF_KH + m * 80 + cn * 2) = f2b(v);
                else
                    *(unsigned short*)(pool + OFF_VT + cn * 208 + m * 2) = f2b(v);
            }
        }
    }
    __syncthreads();

    for (int i = tid; i < 80; i += 256) rowsum[i] = 0.f;
    for (int i = tid; i < 320; i += 256) {
        int m = i >> 2, c4 = 80 + ((i & 3) << 2);
        unsigned short z4[4] = {0, 0, 0, 0};
        *(ulonglong1*)(pool + OFF_P + m * 208 + c4 * 2) = *(ulonglong1*)z4;
    }
    __syncthreads();

    for (int t = w; t < 25; t += 4) {
        int mt = t / 5, jt = t % 5;
        int am = min(mt * 16 + cl, NT - 1);
        int bj = min(jt * 16 + cl, NT - 1);
        short8 a = *(const short8*)(pool + OFF_QH + am * 80 + (q << 4));
        short8 bb = *(const short8*)(pool + OFF_KH + bj * 80 + (q << 4));
        float4v s = __builtin_amdgcn_mfma_f32_16x16x32_bf16(
            a, bb, (float4v){0.f, 0.f, 0.f, 0.f}, 0, 0, 0);
        int col = jt * 16 + cl;
        float4 bv = *(const float4*)(Bmat + ((h * 80 + col) * 80) + mt * 16 + (q << 2));
        float rs[4];
        #pragma unroll
        for (int r = 0; r < 4; ++r) {
            int row = mt * 16 + (q << 2) + r;
            float p = exp2f(s[r] + ((const float*)&bv)[r]);
            *(unsigned short*)(pool + OFF_P + row * 208 + col * 2) = f2b(p);
            rs[r] = p;
        }
        #pragma unroll
        for (int off = 1; off < 16; off <<= 1) {
            #pragma unroll
            for (int r = 0; r < 4; ++r) rs[r] += __shfl_xor(rs[r], off, 64);
        }
        if (cl == 0) {
            #pragma unroll
            for (int r = 0; r < 4; ++r)
                atomicAdd(&rowsum[mt * 16 + (q << 2) + r], rs[r]);
        }
    }
    __syncthreads();

    const int npv = (w < 2) ? 3 : 2;
    for (int i = 0; i < npv; ++i) {
        int t = w + 4 * i, mt = t % 5, nt = t / 5;
        float4v a4 = (float4v){0.f, 0.f, 0.f, 0.f};
        #pragma unroll
        for (int ks = 0; ks < 3; ++ks) {
            short8 a = *(const short8*)(pool + OFF_P + (mt * 16 + cl) * 208 + (ks << 6) + (q << 4));
            short8 bb = *(const short8*)(pool + OFF_VT + (nt * 16 + cl) * 208 + (ks << 6) + (q << 4));
            a4 = __builtin_amdgcn_mfma_f32_16x16x32_bf16(a, bb, a4, 0, 0, 0);
        }
        #pragma unroll
        for (int r = 0; r < 4; ++r) {
            int m = mt * 16 + (q << 2) + r;
            if (m < NT) {
                float inv = 1.f / rowsum[m];
                ybuf[xbase + m * DIMC + (h << 5) + nt * 16 + cl] = f2b(a4[r] * inv);
            }
        }
    }
}

// ---------------------------------------------------------------------------
// proj: out[M][256] = ybuf[M][256](bf16) @ proj_w^T(bf16) + pb
// ---------------------------------------------------------------------------
__global__ __launch_bounds__(256) void proj_kernel(
    const unsigned short* __restrict__ ybuf,
    const unsigned short* __restrict__ pwbf,
    const float* __restrict__ pb,
    float* __restrict__ out)
{
    __shared__ __align__(16) char ldsA[128 * 80];
    __shared__ __align__(16) char ldsB[128 * 80];
    const int tid = threadIdx.x;
    const int l = tid & 63, w = tid >> 6;
    const int q = l >> 4, cl = l & 15;
    const int nb = blockIdx.x & 1;
    const size_t arow0 = (size_t)(blockIdx.x >> 1) * 128;
    const int brow0 = nb * 128;
    const int wm = w >> 1, wn = w & 1;

    float4v acc[4][4];
    #pragma unroll
    for (int mi = 0; mi < 4; ++mi)
        #pragma unroll
        for (int ni = 0; ni < 4; ++ni)
            acc[mi][ni] = (float4v){0.f, 0.f, 0.f, 0.f};

    float pbv[4];
    #pragma unroll
    for (int ni = 0; ni < 4; ++ni)
        pbv[ni] = pb[brow0 + wn * 64 + ni * 16 + cl];

    for (int kc = 0; kc < 8; ++kc) {
        if (kc) __syncthreads();
        #pragma unroll
        for (int s = 0; s < 2; ++s) {
            int e = tid + (s << 8);
            int r = e >> 2, c = (e & 3) << 3;
            *(short8*)(ldsA + r * 80 + (c << 1)) =
                *(const short8*)(ybuf + (arow0 + r) * DIMC + (kc << 5) + c);
            *(short8*)(ldsB + r * 80 + (c << 1)) =
                *(const short8*)(pwbf + (size_t)(brow0 + r) * DIMC + (kc << 5) + c);
        }
        __syncthreads();
        short8 af[4], bf[4];
        #pragma unroll
        for (int mi = 0; mi < 4; ++mi)
            af[mi] = *(const short8*)(ldsA + (wm * 64 + mi * 16 + cl) * 80 + (q << 4));
        #pragma unroll
        for (int ni = 0; ni < 4; ++ni)
            bf[ni] = *(const short8*)(ldsB + (wn * 64 + ni * 16 + cl) * 80 + (q << 4));
        #pragma unroll
        for (int mi = 0; mi < 4; ++mi)
            #pragma unroll
            for (int ni = 0; ni < 4; ++ni)
                acc[mi][ni] = __builtin_amdgcn_mfma_f32_16x16x32_bf16(
                    af[mi], bf[ni], acc[mi][ni], 0, 0, 0);
    }

    #pragma unroll
    for (int mi = 0; mi < 4; ++mi) {
        #pragma unroll
        for (int ni = 0; ni < 4; ++ni) {
            int col = brow0 + wn * 64 + ni * 16 + cl;
            #pragma unroll
            for (int r = 0; r < 4; ++r) {
                size_t row = arow0 + wm * 64 + mi * 16 + (q << 2) + r;
                out[row * DIMC + col] = acc[mi][ni][r] + pbv[ni];
            }
        }
    }
}

extern "C" void kernel_launch(void* const* d_in, const int* in_sizes, int n_in,
                              void* d_out, int out_size, void* d_ws, size_t ws_size,
                              hipStream_t stream) {
    const float* x     = (const float*)d_in[0];
    const float* qkv_w = (const float*)d_in[1];
    const float* qkv_b = (const float*)d_in[2];
    const float* btab  = (const float*)d_in[3];
    const float* pw    = (const float*)d_in[4];
    const float* pb    = (const float*)d_in[5];
    const int*   tnp   = (const int*)d_in[6];
    float* out = (float*)d_out;

    unsigned short* wqkv_bf = (unsigned short*)((char*)d_ws + WS_WQKV);
    unsigned short* pwbf    = (unsigned short*)((char*)d_ws + WS_PW);
    float*          Bmat    = (float*)((char*)d_ws + WS_BMAT);
    unsigned short* xbf     = (unsigned short*)((char*)d_ws + WS_XBF);
    unsigned short* ybuf    = (unsigned short*)((char*)d_ws + WS_XBF);  // overlay
    unsigned short* qkvbuf  = (unsigned short*)((char*)d_ws + WS_QKV);

    prep_kernel<<<4096, 256, 0, stream>>>(qkv_w, pw, btab, tnp, x,
                                          wqkv_bf, pwbf, Bmat, xbf);

    if (ws_size >= WS_NEEDED) {
        qkv_gemm_kernel<<<(MTOK / 128) * 6, 256, 0, stream>>>(xbf, wqkv_bf, qkv_b, qkvbuf);
        attn_core_kernel<<<B_WIN * NH, 256, 0, stream>>>(qkvbuf, Bmat, ybuf);
    } else {
        attn_fused_kernel<<<B_WIN * NH, 256, 0, stream>>>(x, wqkv_bf, qkv_b, Bmat, ybuf);
    }
    proj_kernel<<<(MTOK / 128) * 2, 256, 0, stream>>>(ybuf, pwbf, pb, out);
}